// Round 5
// baseline (1982.148 us; speedup 1.0000x reference)
//
#include <hip/hip_runtime.h>
#include <cstdint>
#include <cstddef>

#define E 1024
#define NB 32768
#define BM 128
#define BN 128

typedef __attribute__((ext_vector_type(4))) float f32x4;
typedef __attribute__((ext_vector_type(8))) short bf16x8;
typedef __attribute__((ext_vector_type(4))) short s16x4;

__device__ __forceinline__ short f2bfs(float x) {
    __bf16 h = (__bf16)x;
    return __builtin_bit_cast(short, h);
}
__device__ __forceinline__ float bf2f(short u) {
    union { unsigned u; float f; } v;
    v.u = ((unsigned)(unsigned short)u) << 16;
    return v.f;
}
__device__ __forceinline__ bf16x8 cvt8(f32x4 lo, f32x4 hi) {
    bf16x8 r;
#pragma unroll
    for (int j = 0; j < 4; ++j) { r[j] = f2bfs(lo[j]); r[j + 4] = f2bfs(hi[j]); }
    return r;
}

__device__ __forceinline__ void gload16(const void* g, void* l) {
    __builtin_amdgcn_global_load_lds(
        (__attribute__((address_space(1))) void*)g,
        (__attribute__((address_space(3))) void*)l, 16, 0, 0);
}

// ---------------- transpose f32 -> bf16 (Wv -> WvT) ----------------
__global__ __launch_bounds__(256) void wv_transpose(const float* W0, short* T0,
                                                    const float* W1, short* T1) {
    const float* W = blockIdx.z ? W1 : W0;
    short* T = blockIdx.z ? T1 : T0;
    __shared__ float tile[32][33];
    const int j0 = blockIdx.x * 32, i0 = blockIdx.y * 32;
    const int tx = threadIdx.x, ty = threadIdx.y; // (32,8)
#pragma unroll
    for (int r = 0; r < 4; ++r)
        tile[ty + 8 * r][tx] = W[(size_t)(i0 + ty + 8 * r) * E + j0 + tx];
    __syncthreads();
#pragma unroll
    for (int r = 0; r < 4; ++r)
        T[(size_t)(j0 + ty + 8 * r) * E + i0 + tx] = f2bfs(tile[tx][ty + 8 * r]);
}

// ---------------- c[n] = scale * (sum_i O[n][i]*bv[i] + ob[n]) ----------------
__global__ __launch_bounds__(256) void bias_fuse(const float* O0, const float* bv0, const float* ob0, const float* s0, float* c0,
                                                 const float* O1, const float* bv1, const float* ob1, const float* s1, float* c1) {
    const float* O  = blockIdx.z ? O1 : O0;
    const float* bv = blockIdx.z ? bv1 : bv0;
    const float* ob = blockIdx.z ? ob1 : ob0;
    const float* sc = blockIdx.z ? s1 : s0;
    float* c = blockIdx.z ? c1 : c0;
    const int n = blockIdx.x, t = threadIdx.x;
    float s = 0.f;
    for (int i = t; i < E; i += 256) s += O[(size_t)n * E + i] * bv[i];
#pragma unroll
    for (int o = 32; o; o >>= 1) s += __shfl_down(s, o);
    __shared__ float rs[4];
    if ((t & 63) == 0) rs[t >> 6] = s;
    __syncthreads();
    if (t == 0) c[n] = sc[0] * (rs[0] + rs[1] + rs[2] + rs[3] + ob[n]);
}

// ---------------- small GEMM (round-3 proven): C = scale * A @ B^T ----------------
struct GemmArgs {
    const char* A;
    const short* B;
    const float* bias;
    const float* scale;
    char* C;
};

template <bool ABF16>
__global__ __launch_bounds__(256, ABF16 ? 4 : 3) void gemm_bt(GemmArgs g0, GemmArgs g1,
                                                              int mb, int arstride, int crstride) {
    const int nwg = gridDim.x;
    const int q = nwg >> 3;
    const int wgid = (blockIdx.x & 7) * q + (blockIdx.x >> 3);
    const int per = mb * 8;
    const int z = wgid / per;
    const int rem = wgid - z * per;
    const int bx = rem >> 3;
    const int by = rem & 7;
    GemmArgs ga = z ? g1 : g0;

    constexpr int ABYTES = ABF16 ? 8192 : 16384;
    constexpr int BUFB = ABYTES + 8192;
    __shared__ __align__(16) char lds[2][BUFB];

    const int t = threadIdx.x;
    const int l = t & 63, w = t >> 6;
    const int am0 = bx * BM, bn0 = by * BN;

    const char* gA[ABF16 ? 2 : 4];
    if constexpr (ABF16) {
#pragma unroll
        for (int i = 0; i < 2; ++i) {
            int c = i * 4 + w;
            int row = c * 16 + (l >> 2);
            int slot = (l & 3) ^ ((row >> 1) & 3);
            gA[i] = ga.A + (size_t)(am0 + row) * arstride + slot * 16;
        }
    } else {
#pragma unroll
        for (int i = 0; i < 4; ++i) {
            int c = i * 4 + w;
            int row = c * 8 + (l >> 3);
            int slot = (l & 7) ^ (row & 7);
            gA[i] = ga.A + (size_t)(am0 + row) * arstride + slot * 16;
        }
    }
    const short* gB[2];
#pragma unroll
    for (int i = 0; i < 2; ++i) {
        int c = i * 4 + w;
        int row = c * 16 + (l >> 2);
        int slot = (l & 3) ^ ((row >> 1) & 3);
        gB[i] = ga.B + (size_t)(bn0 + row) * E + slot * 8;
    }

    auto stage = [&](int buf, int kt) {
        if constexpr (ABF16) {
#pragma unroll
            for (int i = 0; i < 2; ++i)
                gload16(gA[i] + (size_t)kt * 2, &lds[buf][(i * 4 + w) * 1024]);
        } else {
#pragma unroll
            for (int i = 0; i < 4; ++i)
                gload16(gA[i] + (size_t)kt * 4, &lds[buf][(i * 4 + w) * 1024]);
        }
#pragma unroll
        for (int i = 0; i < 2; ++i)
            gload16(gB[i] + kt, &lds[buf][ABYTES + (i * 4 + w) * 1024]);
    };

    const int wm = w >> 1, wn = w & 1;
    const int r16 = l & 15, kg = l >> 4;
    int aoff[4][ABF16 ? 1 : 2], boff[4];
#pragma unroll
    for (int m = 0; m < 4; ++m) {
        int row = wm * 64 + m * 16 + r16;
        if constexpr (ABF16) {
            aoff[m][0] = row * 64 + (kg ^ ((row >> 1) & 3)) * 16;
        } else {
            aoff[m][0] = row * 128 + ((kg * 2) ^ (row & 7)) * 16;
            aoff[m][1] = row * 128 + ((kg * 2 + 1) ^ (row & 7)) * 16;
        }
    }
#pragma unroll
    for (int n = 0; n < 4; ++n) {
        int row = wn * 64 + n * 16 + r16;
        boff[n] = ABYTES + row * 64 + (kg ^ ((row >> 1) & 3)) * 16;
    }

    f32x4 acc[4][4] = {};

    auto compute = [&](int buf) {
        bf16x8 a[4], b[4];
#pragma unroll
        for (int m = 0; m < 4; ++m) {
            if constexpr (ABF16) {
                a[m] = *(const bf16x8*)&lds[buf][aoff[m][0]];
            } else {
                f32x4 lo = *(const f32x4*)&lds[buf][aoff[m][0]];
                f32x4 hi = *(const f32x4*)&lds[buf][aoff[m][1]];
                a[m] = cvt8(lo, hi);
            }
        }
#pragma unroll
        for (int n = 0; n < 4; ++n)
            b[n] = *(const bf16x8*)&lds[buf][boff[n]];
#pragma unroll
        for (int m = 0; m < 4; ++m)
#pragma unroll
            for (int n = 0; n < 4; ++n)
                acc[m][n] = __builtin_amdgcn_mfma_f32_16x16x32_bf16(a[m], b[n], acc[m][n], 0, 0, 0);
    };

    stage(0, 0);
    __syncthreads();
#pragma unroll 1
    for (int kt = 0; kt < E; kt += 64) {
        stage(1, kt + 32);
        compute(0);
        __syncthreads();
        if (kt + 64 < E) stage(0, kt + 64);
        compute(1);
        __syncthreads();
    }

    const int ccol0 = bn0 + wn * 64 + r16;
    const int crow0 = am0 + wm * 64 + kg * 4;
    const float sc = ga.scale ? ga.scale[0] : 1.f;
    float bn_[4];
#pragma unroll
    for (int n = 0; n < 4; ++n) bn_[n] = ga.bias ? ga.bias[ccol0 + n * 16] : 0.f;
#pragma unroll
    for (int m = 0; m < 4; ++m)
#pragma unroll
        for (int n = 0; n < 4; ++n)
#pragma unroll
            for (int qq = 0; qq < 4; ++qq) {
                int row = crow0 + m * 16 + qq;
                int col = ccol0 + n * 16;
                short* p = (short*)(ga.C + (size_t)row * crstride) + col;
                *p = f2bfs(acc[m][n][qq] * sc + bn_[n]);
            }
}

// ============ fused: out = LN(q_emb + (kv_emb @ M^T + c)) * g + b ============
// Tile: 64 rows x full 1024 cols, 8 waves. BK=32.
// LDS 72KB (A dbuf 2x4KB @0, B single 64KB @8192) -> 2 blocks/CU.
// B correctness: barrier (readers done) -> stageB overwrite -> drain barrier.
struct FArgs {
    const float* kv;   // [32768][1024] f32  (GEMM A)
    const short* M;    // [1024][1024] bf16  [n][k], alpha folded
    const float* c;    // [1024] f32, alpha folded
    const float* q;    // [32768][1024] f32  (residual emb)
    const float* g;
    const float* b;
    float* out;        // [32768][1024] f32
};

#define B0OFF 8192

__global__ __launch_bounds__(512, 4) void fused_gemm_ln(FArgs f0, FArgs f1) {
    // pair-scheduling swizzle: consecutive slots on one XCD alternate tables at the
    // SAME mb, so the pair shares both emb row-panels (kv of one = residual of other).
    const int bid = blockIdx.x;
    const int u = bid >> 3, xcd = bid & 7;
    const int z = u & 1;
    const int mb = xcd * 64 + (u >> 1);
    const FArgs fa = z ? f1 : f0;
    const int r0 = mb * 64;

    __shared__ __align__(16) char lds[73728];

    const int t = threadIdx.x;
    const int l = t & 63, w = t >> 6;
    const int r16 = l & 15, kg = l >> 4;

    // B staging map: global 16B-chunk gi = c*512 + t; row = gi>>2, slot = gi&3
    int bsrc[8];
#pragma unroll
    for (int c = 0; c < 8; ++c) {
        int gi = c * 512 + t;
        int row = gi >> 2, slot = gi & 3;
        int ss = slot ^ ((row >> 1) & 3);   // inverse swizzle on source
        bsrc[c] = row * 2048 + ss * 16;
    }
    // A staging: thread -> (row, 16B-f32-chunk)
    const int ar = t >> 3, ach = t & 7;
    const float* asrc = fa.kv + (size_t)(r0 + ar) * E + ach * 4;
    const int awoff = ar * 64 + (((ach >> 1) ^ ((ar >> 1) & 3)) * 16) + (ach & 1) * 8;

    // read-side swizzled offsets
    int aoff[4], boff[8];
#pragma unroll
    for (int m = 0; m < 4; ++m) {
        int row = m * 16 + r16;
        aoff[m] = row * 64 + (kg ^ ((row >> 1) & 3)) * 16;
    }
#pragma unroll
    for (int n = 0; n < 8; ++n) {
        int row = w * 128 + n * 16 + r16;
        boff[n] = B0OFF + row * 64 + (kg ^ ((row >> 1) & 3)) * 16;
    }

    f32x4 acc[4][8] = {};

    auto stageB = [&](int kt) {
#pragma unroll
        for (int c = 0; c < 8; ++c)
            gload16((const char*)fa.M + bsrc[c] + kt * 2,
                    &lds[B0OFF + c * 8192 + w * 1024]);
    };
    auto commitA = [&](int buf, f32x4 av) {
        s16x4 v;
#pragma unroll
        for (int j = 0; j < 4; ++j) v[j] = f2bfs(av[j]);
        *(s16x4*)&lds[buf * 4096 + awoff] = v;
    };
    auto compute = [&](int buf) {
        bf16x8 a[4], b[8];
#pragma unroll
        for (int m = 0; m < 4; ++m)
            a[m] = *(const bf16x8*)&lds[buf * 4096 + aoff[m]];
#pragma unroll
        for (int n = 0; n < 8; ++n)
            b[n] = *(const bf16x8*)&lds[boff[n]];
#pragma unroll
        for (int m = 0; m < 4; ++m)
#pragma unroll
            for (int n = 0; n < 8; ++n)
                acc[m][n] = __builtin_amdgcn_mfma_f32_16x16x32_bf16(a[m], b[n], acc[m][n], 0, 0, 0);
    };

    // prologue: B(0), A(0) staged; A(32) prefetched to reg
    f32x4 a = *(const f32x4*)(asrc);
    stageB(0);
    commitA(0, a);
    a = *(const f32x4*)(asrc + 32);
    __syncthreads();

#pragma unroll 1
    for (int kt = 0; kt < E; kt += 64) {
        compute(0);                           // B(kt), A buf0
        commitA(1, a);                        // A(kt+32)
        if (kt + 64 < E) a = *(const f32x4*)(asrc + kt + 64);
        __syncthreads();                      // all B(kt) reads done
        stageB(kt + 32);                      // overwrite B
        __syncthreads();                      // drain (vmcnt+lgkm)
        compute(1);                           // B(kt+32), A buf1
        if (kt + 64 < E) {
            commitA(0, a);                    // A(kt+64)
            a = *(const f32x4*)(asrc + kt + 96);
            __syncthreads();
            stageB(kt + 64);
            __syncthreads();
        }
    }
    __syncthreads();   // main loop fully done; LDS free for LN scratch

    // ---- epilogue: residual + LayerNorm ----
    float* S  = (float*)lds;            // [64][8] row sums
    float* Q  = (float*)(lds + 2048);   // [64][8] row sumsq
    float* CB = (float*)(lds + 4096);   // [64][2] mean,rstd

    const int colbase = w * 128 + r16;
    float cf[8];
#pragma unroll
    for (int n = 0; n < 8; ++n) cf[n] = fa.c[colbase + n * 16];

    float sum_[4][4] = {}, sq_[4][4] = {};
#pragma unroll
    for (int m = 0; m < 4; ++m) {
#pragma unroll
        for (int n = 0; n < 8; ++n) {
#pragma unroll
            for (int qq = 0; qq < 4; ++qq) {
                int lrow = m * 16 + kg * 4 + qq;
                float x = acc[m][n][qq] + cf[n] + fa.q[(size_t)(r0 + lrow) * E + colbase + n * 16];
                acc[m][n][qq] = x;
                sum_[m][qq] += x;
                sq_[m][qq] += x * x;
            }
        }
    }
#pragma unroll
    for (int m = 0; m < 4; ++m)
#pragma unroll
        for (int qq = 0; qq < 4; ++qq)
#pragma unroll
            for (int o = 1; o < 16; o <<= 1) {
                sum_[m][qq] += __shfl_xor(sum_[m][qq], o);
                sq_[m][qq] += __shfl_xor(sq_[m][qq], o);
            }
#pragma unroll
    for (int m = 0; m < 4; ++m)
#pragma unroll
        for (int qq = 0; qq < 4; ++qq)
            if (r16 == m * 4 + qq) {
                int lrow = m * 16 + kg * 4 + qq;
                S[lrow * 8 + w] = sum_[m][qq];
                Q[lrow * 8 + w] = sq_[m][qq];
            }
    __syncthreads();
    if (t < 64) {
        f32x4 s0 = *(const f32x4*)(S + t * 8);
        f32x4 s1 = *(const f32x4*)(S + t * 8 + 4);
        f32x4 q0 = *(const f32x4*)(Q + t * 8);
        f32x4 q1 = *(const f32x4*)(Q + t * 8 + 4);
        float ss = s0[0] + s0[1] + s0[2] + s0[3] + s1[0] + s1[1] + s1[2] + s1[3];
        float qs = q0[0] + q0[1] + q0[2] + q0[3] + q1[0] + q1[1] + q1[2] + q1[3];
        float mean = ss * (1.0f / E);
        float var = qs * (1.0f / E) - mean * mean;
        CB[t * 2] = mean;
        CB[t * 2 + 1] = rsqrtf(var + 1e-5f);
    }
    __syncthreads();

    float gf[8], bf_[8];
#pragma unroll
    for (int n = 0; n < 8; ++n) {
        gf[n] = fa.g[colbase + n * 16];
        bf_[n] = fa.b[colbase + n * 16];
    }
#pragma unroll
    for (int m = 0; m < 4; ++m)
#pragma unroll
        for (int qq = 0; qq < 4; ++qq) {
            int lrow = m * 16 + kg * 4 + qq;
            float mean = CB[lrow * 2], rstd = CB[lrow * 2 + 1];
            float* op = fa.out + (size_t)(r0 + lrow) * E + colbase;
#pragma unroll
            for (int n = 0; n < 8; ++n)
                op[n * 16] = (acc[m][n][qq] - mean) * rstd * gf[n] + bf_[n];
        }
}

extern "C" void kernel_launch(void* const* d_in, const int* in_sizes, int n_in,
                              void* d_out, int out_size, void* d_ws, size_t ws_size,
                              hipStream_t stream) {
    const float* user_emb = (const float*)d_in[0];
    const float* item_emb = (const float*)d_in[1];
    const float* u2i_in_w = (const float*)d_in[2];
    const float* u2i_in_b = (const float*)d_in[3];
    const float* u2i_out_w = (const float*)d_in[4];
    const float* u2i_out_b = (const float*)d_in[5];
    const float* i2u_in_w = (const float*)d_in[6];
    const float* i2u_in_b = (const float*)d_in[7];
    const float* i2u_out_w = (const float*)d_in[8];
    const float* i2u_out_b = (const float*)d_in[9];
    const float* user_g = (const float*)d_in[10];
    const float* user_b = (const float*)d_in[11];
    const float* item_g = (const float*)d_in[12];
    const float* item_b = (const float*)d_in[13];
    const float* alpha = (const float*)d_in[14];
    const float* beta = (const float*)d_in[15];

    float* out_u = (float*)d_out;
    float* out_i = out_u + (size_t)NB * E;

    // workspace (~8.4 MB)
    short* WvT1 = (short*)d_ws;
    short* WvT2 = WvT1 + (size_t)E * E;
    short* M1 = WvT2 + (size_t)E * E;
    short* M2 = M1 + (size_t)E * E;
    float* c1 = (float*)(M2 + (size_t)E * E);
    float* c2 = c1 + E;

    const dim3 b256(256);

    // 1) WvT = transpose(in_w[2E:3E]) in bf16
    wv_transpose<<<dim3(32, 32, 2), dim3(32, 8), 0, stream>>>(
        u2i_in_w + 2 * (size_t)E * E, WvT1, i2u_in_w + 2 * (size_t)E * E, WvT2);

    // 2) c = scale * (O @ bv + ob)
    bias_fuse<<<dim3(E, 1, 2), b256, 0, stream>>>(
        u2i_out_w, u2i_in_b + 2 * E, u2i_out_b, alpha, c1,
        i2u_out_w, i2u_in_b + 2 * E, i2u_out_b, beta, c2);

    // 3) M = scale * (O @ Wv)   bf16 [n][k]
    gemm_bt<false><<<dim3(8 * 8 * 2), b256, 0, stream>>>(
        GemmArgs{(const char*)u2i_out_w, WvT1, nullptr, alpha, (char*)M1},
        GemmArgs{(const char*)i2u_out_w, WvT2, nullptr, beta, (char*)M2},
        8, 4096, 2048);

    // 4) fused GEMM + residual + LayerNorm (1024 blocks x 512 threads, 2 blocks/CU)
    fused_gemm_ln<<<dim3(1024), dim3(512), 0, stream>>>(
        FArgs{item_emb, M1, c1, user_emb, user_g, user_b, out_u},
        FArgs{user_emb, M2, c2, item_emb, item_g, item_b, out_i});
}

// Round 6
// 367.218 us; speedup vs baseline: 5.3977x; 5.3977x over previous
//
#include <hip/hip_runtime.h>
#include <cstdint>
#include <cstddef>

#define E 1024
#define NB 32768
#define BM 128
#define BN 128

typedef __attribute__((ext_vector_type(4))) float f32x4;
typedef __attribute__((ext_vector_type(8))) short bf16x8;
typedef __attribute__((ext_vector_type(4))) short s16x4;

__device__ __forceinline__ short f2bfs(float x) {
    __bf16 h = (__bf16)x;
    return __builtin_bit_cast(short, h);
}
__device__ __forceinline__ float bf2f(short u) {
    union { unsigned u; float f; } v;
    v.u = ((unsigned)(unsigned short)u) << 16;
    return v.f;
}
__device__ __forceinline__ bf16x8 cvt8(f32x4 lo, f32x4 hi) {
    bf16x8 r;
#pragma unroll
    for (int j = 0; j < 4; ++j) { r[j] = f2bfs(lo[j]); r[j + 4] = f2bfs(hi[j]); }
    return r;
}

__device__ __forceinline__ void gload16(const void* g, void* l) {
    __builtin_amdgcn_global_load_lds(
        (__attribute__((address_space(1))) void*)g,
        (__attribute__((address_space(3))) void*)l, 16, 0, 0);
}

// ---------------- transpose f32 -> bf16 (Wv -> WvT) ----------------
__global__ __launch_bounds__(256) void wv_transpose(const float* W0, short* T0,
                                                    const float* W1, short* T1) {
    const float* W = blockIdx.z ? W1 : W0;
    short* T = blockIdx.z ? T1 : T0;
    __shared__ float tile[32][33];
    const int j0 = blockIdx.x * 32, i0 = blockIdx.y * 32;
    const int tx = threadIdx.x, ty = threadIdx.y; // (32,8)
#pragma unroll
    for (int r = 0; r < 4; ++r)
        tile[ty + 8 * r][tx] = W[(size_t)(i0 + ty + 8 * r) * E + j0 + tx];
    __syncthreads();
#pragma unroll
    for (int r = 0; r < 4; ++r)
        T[(size_t)(j0 + ty + 8 * r) * E + i0 + tx] = f2bfs(tile[tx][ty + 8 * r]);
}

// ---------------- c[n] = scale * (sum_i O[n][i]*bv[i] + ob[n]) ----------------
__global__ __launch_bounds__(256) void bias_fuse(const float* O0, const float* bv0, const float* ob0, const float* s0, float* c0,
                                                 const float* O1, const float* bv1, const float* ob1, const float* s1, float* c1) {
    const float* O  = blockIdx.z ? O1 : O0;
    const float* bv = blockIdx.z ? bv1 : bv0;
    const float* ob = blockIdx.z ? ob1 : ob0;
    const float* sc = blockIdx.z ? s1 : s0;
    float* c = blockIdx.z ? c1 : c0;
    const int n = blockIdx.x, t = threadIdx.x;
    float s = 0.f;
    for (int i = t; i < E; i += 256) s += O[(size_t)n * E + i] * bv[i];
#pragma unroll
    for (int o = 32; o; o >>= 1) s += __shfl_down(s, o);
    __shared__ float rs[4];
    if ((t & 63) == 0) rs[t >> 6] = s;
    __syncthreads();
    if (t == 0) c[n] = sc[0] * (rs[0] + rs[1] + rs[2] + rs[3] + ob[n]);
}

// ---------------- small GEMM (round-3 proven): C = scale * A @ B^T ----------------
struct GemmArgs {
    const char* A;
    const short* B;
    const float* bias;
    const float* scale;
    char* C;
};

template <bool ABF16>
__global__ __launch_bounds__(256, ABF16 ? 4 : 3) void gemm_bt(GemmArgs g0, GemmArgs g1,
                                                              int mb, int arstride, int crstride) {
    const int nwg = gridDim.x;
    const int q = nwg >> 3;
    const int wgid = (blockIdx.x & 7) * q + (blockIdx.x >> 3);
    const int per = mb * 8;
    const int z = wgid / per;
    const int rem = wgid - z * per;
    const int bx = rem >> 3;
    const int by = rem & 7;
    GemmArgs ga = z ? g1 : g0;

    constexpr int ABYTES = ABF16 ? 8192 : 16384;
    constexpr int BUFB = ABYTES + 8192;
    __shared__ __align__(16) char lds[2][BUFB];

    const int t = threadIdx.x;
    const int l = t & 63, w = t >> 6;
    const int am0 = bx * BM, bn0 = by * BN;

    const char* gA[ABF16 ? 2 : 4];
    if constexpr (ABF16) {
#pragma unroll
        for (int i = 0; i < 2; ++i) {
            int c = i * 4 + w;
            int row = c * 16 + (l >> 2);
            int slot = (l & 3) ^ ((row >> 1) & 3);
            gA[i] = ga.A + (size_t)(am0 + row) * arstride + slot * 16;
        }
    } else {
#pragma unroll
        for (int i = 0; i < 4; ++i) {
            int c = i * 4 + w;
            int row = c * 8 + (l >> 3);
            int slot = (l & 7) ^ (row & 7);
            gA[i] = ga.A + (size_t)(am0 + row) * arstride + slot * 16;
        }
    }
    const short* gB[2];
#pragma unroll
    for (int i = 0; i < 2; ++i) {
        int c = i * 4 + w;
        int row = c * 16 + (l >> 2);
        int slot = (l & 3) ^ ((row >> 1) & 3);
        gB[i] = ga.B + (size_t)(bn0 + row) * E + slot * 8;
    }

    auto stage = [&](int buf, int kt) {
        if constexpr (ABF16) {
#pragma unroll
            for (int i = 0; i < 2; ++i)
                gload16(gA[i] + (size_t)kt * 2, &lds[buf][(i * 4 + w) * 1024]);
        } else {
#pragma unroll
            for (int i = 0; i < 4; ++i)
                gload16(gA[i] + (size_t)kt * 4, &lds[buf][(i * 4 + w) * 1024]);
        }
#pragma unroll
        for (int i = 0; i < 2; ++i)
            gload16(gB[i] + kt, &lds[buf][ABYTES + (i * 4 + w) * 1024]);
    };

    const int wm = w >> 1, wn = w & 1;
    const int r16 = l & 15, kg = l >> 4;
    int aoff[4][ABF16 ? 1 : 2], boff[4];
#pragma unroll
    for (int m = 0; m < 4; ++m) {
        int row = wm * 64 + m * 16 + r16;
        if constexpr (ABF16) {
            aoff[m][0] = row * 64 + (kg ^ ((row >> 1) & 3)) * 16;
        } else {
            aoff[m][0] = row * 128 + ((kg * 2) ^ (row & 7)) * 16;
            aoff[m][1] = row * 128 + ((kg * 2 + 1) ^ (row & 7)) * 16;
        }
    }
#pragma unroll
    for (int n = 0; n < 4; ++n) {
        int row = wn * 64 + n * 16 + r16;
        boff[n] = ABYTES + row * 64 + (kg ^ ((row >> 1) & 3)) * 16;
    }

    f32x4 acc[4][4] = {};

    auto compute = [&](int buf) {
        bf16x8 a[4], b[4];
#pragma unroll
        for (int m = 0; m < 4; ++m) {
            if constexpr (ABF16) {
                a[m] = *(const bf16x8*)&lds[buf][aoff[m][0]];
            } else {
                f32x4 lo = *(const f32x4*)&lds[buf][aoff[m][0]];
                f32x4 hi = *(const f32x4*)&lds[buf][aoff[m][1]];
                a[m] = cvt8(lo, hi);
            }
        }
#pragma unroll
        for (int n = 0; n < 4; ++n)
            b[n] = *(const bf16x8*)&lds[buf][boff[n]];
#pragma unroll
        for (int m = 0; m < 4; ++m)
#pragma unroll
            for (int n = 0; n < 4; ++n)
                acc[m][n] = __builtin_amdgcn_mfma_f32_16x16x32_bf16(a[m], b[n], acc[m][n], 0, 0, 0);
    };

    stage(0, 0);
    __syncthreads();
#pragma unroll 1
    for (int kt = 0; kt < E; kt += 64) {
        stage(1, kt + 32);
        compute(0);
        __syncthreads();
        if (kt + 64 < E) stage(0, kt + 64);
        compute(1);
        __syncthreads();
    }

    const int ccol0 = bn0 + wn * 64 + r16;
    const int crow0 = am0 + wm * 64 + kg * 4;
    const float sc = ga.scale ? ga.scale[0] : 1.f;
    float bn_[4];
#pragma unroll
    for (int n = 0; n < 4; ++n) bn_[n] = ga.bias ? ga.bias[ccol0 + n * 16] : 0.f;
#pragma unroll
    for (int m = 0; m < 4; ++m)
#pragma unroll
        for (int n = 0; n < 4; ++n)
#pragma unroll
            for (int qq = 0; qq < 4; ++qq) {
                int row = crow0 + m * 16 + qq;
                int col = ccol0 + n * 16;
                short* p = (short*)(ga.C + (size_t)row * crstride) + col;
                *p = f2bfs(acc[m][n][qq] * sc + bn_[n]);
            }
}

// ============ fused: out = LN(q_emb + (kv_emb @ M^T + c)) * g + b ============
// Tile: 64 rows x full 1024 cols, 8 waves. BK=32.
// LDS 72KB (A dbuf 2x4KB @0, B single 64KB @8192) -> 2 blocks/CU (LDS-limited).
// __launch_bounds__(512,2): VGPR cap 256 — the acc[4][8] (128 VGPR) must NOT
// spill; (512,4) capped at 128 VGPR and spilled acc to scratch (round-5: 7.9 GB
// of scratch traffic, 6x regression).
struct FArgs {
    const float* kv;   // [32768][1024] f32  (GEMM A)
    const short* M;    // [1024][1024] bf16  [n][k], alpha folded
    const float* c;    // [1024] f32, alpha folded
    const float* q;    // [32768][1024] f32  (residual emb)
    const float* g;
    const float* b;
    float* out;        // [32768][1024] f32
};

#define B0OFF 8192

__global__ __launch_bounds__(512, 2) void fused_gemm_ln(FArgs f0, FArgs f1) {
    // pair-scheduling swizzle: consecutive slots on one XCD alternate tables at the
    // SAME mb, so the pair shares both emb row-panels (kv of one = residual of other).
    const int bid = blockIdx.x;
    const int u = bid >> 3, xcd = bid & 7;
    const int z = u & 1;
    const int mb = xcd * 64 + (u >> 1);
    const FArgs fa = z ? f1 : f0;
    const int r0 = mb * 64;

    __shared__ __align__(16) char lds[73728];

    const int t = threadIdx.x;
    const int l = t & 63, w = t >> 6;
    const int r16 = l & 15, kg = l >> 4;

    // B staging map: global 16B-chunk gi = c*512 + t; row = gi>>2, slot = gi&3
    int bsrc[8];
#pragma unroll
    for (int c = 0; c < 8; ++c) {
        int gi = c * 512 + t;
        int row = gi >> 2, slot = gi & 3;
        int ss = slot ^ ((row >> 1) & 3);   // inverse swizzle on source
        bsrc[c] = row * 2048 + ss * 16;
    }
    // A staging: thread -> (row, 16B-f32-chunk)
    const int ar = t >> 3, ach = t & 7;
    const float* asrc = fa.kv + (size_t)(r0 + ar) * E + ach * 4;
    const int awoff = ar * 64 + (((ach >> 1) ^ ((ar >> 1) & 3)) * 16) + (ach & 1) * 8;

    // read-side swizzled offsets
    int aoff[4], boff[8];
#pragma unroll
    for (int m = 0; m < 4; ++m) {
        int row = m * 16 + r16;
        aoff[m] = row * 64 + (kg ^ ((row >> 1) & 3)) * 16;
    }
#pragma unroll
    for (int n = 0; n < 8; ++n) {
        int row = w * 128 + n * 16 + r16;
        boff[n] = B0OFF + row * 64 + (kg ^ ((row >> 1) & 3)) * 16;
    }

    f32x4 acc[4][8] = {};

    auto stageB = [&](int kt) {
#pragma unroll
        for (int c = 0; c < 8; ++c)
            gload16((const char*)fa.M + bsrc[c] + kt * 2,
                    &lds[B0OFF + c * 8192 + w * 1024]);
    };
    auto commitA = [&](int buf, f32x4 av) {
        s16x4 v;
#pragma unroll
        for (int j = 0; j < 4; ++j) v[j] = f2bfs(av[j]);
        *(s16x4*)&lds[buf * 4096 + awoff] = v;
    };
    auto compute = [&](int buf) {
        bf16x8 a[4], b[8];
#pragma unroll
        for (int m = 0; m < 4; ++m)
            a[m] = *(const bf16x8*)&lds[buf * 4096 + aoff[m]];
#pragma unroll
        for (int n = 0; n < 8; ++n)
            b[n] = *(const bf16x8*)&lds[boff[n]];
#pragma unroll
        for (int m = 0; m < 4; ++m)
#pragma unroll
            for (int n = 0; n < 8; ++n)
                acc[m][n] = __builtin_amdgcn_mfma_f32_16x16x32_bf16(a[m], b[n], acc[m][n], 0, 0, 0);
    };

    // prologue: B(0), A(0) staged; A(32) prefetched to reg
    f32x4 a = *(const f32x4*)(asrc);
    stageB(0);
    commitA(0, a);
    a = *(const f32x4*)(asrc + 32);
    __syncthreads();

#pragma unroll 1
    for (int kt = 0; kt < E; kt += 64) {
        compute(0);                           // B(kt), A buf0
        commitA(1, a);                        // A(kt+32)
        if (kt + 64 < E) a = *(const f32x4*)(asrc + kt + 64);
        __syncthreads();                      // all B(kt) reads done
        stageB(kt + 32);                      // overwrite B
        __syncthreads();                      // drain (vmcnt+lgkm)
        compute(1);                           // B(kt+32), A buf1
        if (kt + 64 < E) {
            commitA(0, a);                    // A(kt+64)
            a = *(const f32x4*)(asrc + kt + 96);
            __syncthreads();
            stageB(kt + 64);
            __syncthreads();
        }
    }
    __syncthreads();   // main loop fully done; LDS free for LN scratch

    // ---- epilogue: residual + LayerNorm ----
    float* S  = (float*)lds;            // [64][8] row sums
    float* Q  = (float*)(lds + 2048);   // [64][8] row sumsq
    float* CB = (float*)(lds + 4096);   // [64][2] mean,rstd

    const int colbase = w * 128 + r16;
    float cf[8];
#pragma unroll
    for (int n = 0; n < 8; ++n) cf[n] = fa.c[colbase + n * 16];

    float sum_[4][4] = {}, sq_[4][4] = {};
#pragma unroll
    for (int m = 0; m < 4; ++m) {
#pragma unroll
        for (int n = 0; n < 8; ++n) {
#pragma unroll
            for (int qq = 0; qq < 4; ++qq) {
                int lrow = m * 16 + kg * 4 + qq;
                float x = acc[m][n][qq] + cf[n] + fa.q[(size_t)(r0 + lrow) * E + colbase + n * 16];
                acc[m][n][qq] = x;
                sum_[m][qq] += x;
                sq_[m][qq] += x * x;
            }
        }
    }
#pragma unroll
    for (int m = 0; m < 4; ++m)
#pragma unroll
        for (int qq = 0; qq < 4; ++qq)
#pragma unroll
            for (int o = 1; o < 16; o <<= 1) {
                sum_[m][qq] += __shfl_xor(sum_[m][qq], o);
                sq_[m][qq] += __shfl_xor(sq_[m][qq], o);
            }
#pragma unroll
    for (int m = 0; m < 4; ++m)
#pragma unroll
        for (int qq = 0; qq < 4; ++qq)
            if (r16 == m * 4 + qq) {
                int lrow = m * 16 + kg * 4 + qq;
                S[lrow * 8 + w] = sum_[m][qq];
                Q[lrow * 8 + w] = sq_[m][qq];
            }
    __syncthreads();
    if (t < 64) {
        f32x4 s0 = *(const f32x4*)(S + t * 8);
        f32x4 s1 = *(const f32x4*)(S + t * 8 + 4);
        f32x4 q0 = *(const f32x4*)(Q + t * 8);
        f32x4 q1 = *(const f32x4*)(Q + t * 8 + 4);
        float ss = s0[0] + s0[1] + s0[2] + s0[3] + s1[0] + s1[1] + s1[2] + s1[3];
        float qs = q0[0] + q0[1] + q0[2] + q0[3] + q1[0] + q1[1] + q1[2] + q1[3];
        float mean = ss * (1.0f / E);
        float var = qs * (1.0f / E) - mean * mean;
        CB[t * 2] = mean;
        CB[t * 2 + 1] = rsqrtf(var + 1e-5f);
    }
    __syncthreads();

    float gf[8], bf_[8];
#pragma unroll
    for (int n = 0; n < 8; ++n) {
        gf[n] = fa.g[colbase + n * 16];
        bf_[n] = fa.b[colbase + n * 16];
    }
#pragma unroll
    for (int m = 0; m < 4; ++m)
#pragma unroll
        for (int qq = 0; qq < 4; ++qq) {
            int lrow = m * 16 + kg * 4 + qq;
            float mean = CB[lrow * 2], rstd = CB[lrow * 2 + 1];
            float* op = fa.out + (size_t)(r0 + lrow) * E + colbase;
#pragma unroll
            for (int n = 0; n < 8; ++n)
                op[n * 16] = (acc[m][n][qq] - mean) * rstd * gf[n] + bf_[n];
        }
}

extern "C" void kernel_launch(void* const* d_in, const int* in_sizes, int n_in,
                              void* d_out, int out_size, void* d_ws, size_t ws_size,
                              hipStream_t stream) {
    const float* user_emb = (const float*)d_in[0];
    const float* item_emb = (const float*)d_in[1];
    const float* u2i_in_w = (const float*)d_in[2];
    const float* u2i_in_b = (const float*)d_in[3];
    const float* u2i_out_w = (const float*)d_in[4];
    const float* u2i_out_b = (const float*)d_in[5];
    const float* i2u_in_w = (const float*)d_in[6];
    const float* i2u_in_b = (const float*)d_in[7];
    const float* i2u_out_w = (const float*)d_in[8];
    const float* i2u_out_b = (const float*)d_in[9];
    const float* user_g = (const float*)d_in[10];
    const float* user_b = (const float*)d_in[11];
    const float* item_g = (const float*)d_in[12];
    const float* item_b = (const float*)d_in[13];
    const float* alpha = (const float*)d_in[14];
    const float* beta = (const float*)d_in[15];

    float* out_u = (float*)d_out;
    float* out_i = out_u + (size_t)NB * E;

    // workspace (~8.4 MB)
    short* WvT1 = (short*)d_ws;
    short* WvT2 = WvT1 + (size_t)E * E;
    short* M1 = WvT2 + (size_t)E * E;
    short* M2 = M1 + (size_t)E * E;
    float* c1 = (float*)(M2 + (size_t)E * E);
    float* c2 = c1 + E;

    const dim3 b256(256);

    // 1) WvT = transpose(in_w[2E:3E]) in bf16
    wv_transpose<<<dim3(32, 32, 2), dim3(32, 8), 0, stream>>>(
        u2i_in_w + 2 * (size_t)E * E, WvT1, i2u_in_w + 2 * (size_t)E * E, WvT2);

    // 2) c = scale * (O @ bv + ob)
    bias_fuse<<<dim3(E, 1, 2), b256, 0, stream>>>(
        u2i_out_w, u2i_in_b + 2 * E, u2i_out_b, alpha, c1,
        i2u_out_w, i2u_in_b + 2 * E, i2u_out_b, beta, c2);

    // 3) M = scale * (O @ Wv)   bf16 [n][k]
    gemm_bt<false><<<dim3(8 * 8 * 2), b256, 0, stream>>>(
        GemmArgs{(const char*)u2i_out_w, WvT1, nullptr, alpha, (char*)M1},
        GemmArgs{(const char*)i2u_out_w, WvT2, nullptr, beta, (char*)M2},
        8, 4096, 2048);

    // 4) fused GEMM + residual + LayerNorm (1024 blocks x 512 threads, 2 blocks/CU)
    fused_gemm_ln<<<dim3(1024), dim3(512), 0, stream>>>(
        FArgs{item_emb, M1, c1, user_emb, user_g, user_b, out_u},
        FArgs{user_emb, M2, c2, item_emb, item_g, item_b, out_i});
}

// Round 7
// 356.205 us; speedup vs baseline: 5.5646x; 1.0309x over previous
//
#include <hip/hip_runtime.h>
#include <cstdint>
#include <cstddef>

#define E 1024
#define NB 32768
#define BM 128
#define BN 128

typedef __attribute__((ext_vector_type(4))) float f32x4;
typedef __attribute__((ext_vector_type(8))) short bf16x8;
typedef __attribute__((ext_vector_type(4))) short s16x4;

__device__ __forceinline__ short f2bfs(float x) {
    __bf16 h = (__bf16)x;
    return __builtin_bit_cast(short, h);
}
__device__ __forceinline__ float bf2f(short u) {
    union { unsigned u; float f; } v;
    v.u = ((unsigned)(unsigned short)u) << 16;
    return v.f;
}
__device__ __forceinline__ bf16x8 cvt8(f32x4 lo, f32x4 hi) {
    bf16x8 r;
#pragma unroll
    for (int j = 0; j < 4; ++j) { r[j] = f2bfs(lo[j]); r[j + 4] = f2bfs(hi[j]); }
    return r;
}

__device__ __forceinline__ void gload16(const void* g, void* l) {
    __builtin_amdgcn_global_load_lds(
        (__attribute__((address_space(1))) void*)g,
        (__attribute__((address_space(3))) void*)l, 16, 0, 0);
}

// ---------------- transpose f32 -> bf16 (Wv -> WvT) ----------------
__global__ __launch_bounds__(256) void wv_transpose(const float* W0, short* T0,
                                                    const float* W1, short* T1) {
    const float* W = blockIdx.z ? W1 : W0;
    short* T = blockIdx.z ? T1 : T0;
    __shared__ float tile[32][33];
    const int j0 = blockIdx.x * 32, i0 = blockIdx.y * 32;
    const int tx = threadIdx.x, ty = threadIdx.y; // (32,8)
#pragma unroll
    for (int r = 0; r < 4; ++r)
        tile[ty + 8 * r][tx] = W[(size_t)(i0 + ty + 8 * r) * E + j0 + tx];
    __syncthreads();
#pragma unroll
    for (int r = 0; r < 4; ++r)
        T[(size_t)(j0 + ty + 8 * r) * E + i0 + tx] = f2bfs(tile[tx][ty + 8 * r]);
}

// ---------------- c[n] = scale * (sum_i O[n][i]*bv[i] + ob[n]) ----------------
__global__ __launch_bounds__(256) void bias_fuse(const float* O0, const float* bv0, const float* ob0, const float* s0, float* c0,
                                                 const float* O1, const float* bv1, const float* ob1, const float* s1, float* c1) {
    const float* O  = blockIdx.z ? O1 : O0;
    const float* bv = blockIdx.z ? bv1 : bv0;
    const float* ob = blockIdx.z ? ob1 : ob0;
    const float* sc = blockIdx.z ? s1 : s0;
    float* c = blockIdx.z ? c1 : c0;
    const int n = blockIdx.x, t = threadIdx.x;
    float s = 0.f;
    for (int i = t; i < E; i += 256) s += O[(size_t)n * E + i] * bv[i];
#pragma unroll
    for (int o = 32; o; o >>= 1) s += __shfl_down(s, o);
    __shared__ float rs[4];
    if ((t & 63) == 0) rs[t >> 6] = s;
    __syncthreads();
    if (t == 0) c[n] = sc[0] * (rs[0] + rs[1] + rs[2] + rs[3] + ob[n]);
}

// ---------------- small GEMM (round-3 proven): C = scale * A @ B^T ----------------
struct GemmArgs {
    const char* A;
    const short* B;
    const float* bias;
    const float* scale;
    char* C;
};

template <bool ABF16>
__global__ __launch_bounds__(256, ABF16 ? 4 : 3) void gemm_bt(GemmArgs g0, GemmArgs g1,
                                                              int mb, int arstride, int crstride) {
    const int nwg = gridDim.x;
    const int q = nwg >> 3;
    const int wgid = (blockIdx.x & 7) * q + (blockIdx.x >> 3);
    const int per = mb * 8;
    const int z = wgid / per;
    const int rem = wgid - z * per;
    const int bx = rem >> 3;
    const int by = rem & 7;
    GemmArgs ga = z ? g1 : g0;

    constexpr int ABYTES = ABF16 ? 8192 : 16384;
    constexpr int BUFB = ABYTES + 8192;
    __shared__ __align__(16) char lds[2][BUFB];

    const int t = threadIdx.x;
    const int l = t & 63, w = t >> 6;
    const int am0 = bx * BM, bn0 = by * BN;

    const char* gA[ABF16 ? 2 : 4];
    if constexpr (ABF16) {
#pragma unroll
        for (int i = 0; i < 2; ++i) {
            int c = i * 4 + w;
            int row = c * 16 + (l >> 2);
            int slot = (l & 3) ^ ((row >> 1) & 3);
            gA[i] = ga.A + (size_t)(am0 + row) * arstride + slot * 16;
        }
    } else {
#pragma unroll
        for (int i = 0; i < 4; ++i) {
            int c = i * 4 + w;
            int row = c * 8 + (l >> 3);
            int slot = (l & 7) ^ (row & 7);
            gA[i] = ga.A + (size_t)(am0 + row) * arstride + slot * 16;
        }
    }
    const short* gB[2];
#pragma unroll
    for (int i = 0; i < 2; ++i) {
        int c = i * 4 + w;
        int row = c * 16 + (l >> 2);
        int slot = (l & 3) ^ ((row >> 1) & 3);
        gB[i] = ga.B + (size_t)(bn0 + row) * E + slot * 8;
    }

    auto stage = [&](int buf, int kt) {
        if constexpr (ABF16) {
#pragma unroll
            for (int i = 0; i < 2; ++i)
                gload16(gA[i] + (size_t)kt * 2, &lds[buf][(i * 4 + w) * 1024]);
        } else {
#pragma unroll
            for (int i = 0; i < 4; ++i)
                gload16(gA[i] + (size_t)kt * 4, &lds[buf][(i * 4 + w) * 1024]);
        }
#pragma unroll
        for (int i = 0; i < 2; ++i)
            gload16(gB[i] + kt, &lds[buf][ABYTES + (i * 4 + w) * 1024]);
    };

    const int wm = w >> 1, wn = w & 1;
    const int r16 = l & 15, kg = l >> 4;
    int aoff[4][ABF16 ? 1 : 2], boff[4];
#pragma unroll
    for (int m = 0; m < 4; ++m) {
        int row = wm * 64 + m * 16 + r16;
        if constexpr (ABF16) {
            aoff[m][0] = row * 64 + (kg ^ ((row >> 1) & 3)) * 16;
        } else {
            aoff[m][0] = row * 128 + ((kg * 2) ^ (row & 7)) * 16;
            aoff[m][1] = row * 128 + ((kg * 2 + 1) ^ (row & 7)) * 16;
        }
    }
#pragma unroll
    for (int n = 0; n < 4; ++n) {
        int row = wn * 64 + n * 16 + r16;
        boff[n] = ABYTES + row * 64 + (kg ^ ((row >> 1) & 3)) * 16;
    }

    f32x4 acc[4][4] = {};

    auto compute = [&](int buf) {
        bf16x8 a[4], b[4];
#pragma unroll
        for (int m = 0; m < 4; ++m) {
            if constexpr (ABF16) {
                a[m] = *(const bf16x8*)&lds[buf][aoff[m][0]];
            } else {
                f32x4 lo = *(const f32x4*)&lds[buf][aoff[m][0]];
                f32x4 hi = *(const f32x4*)&lds[buf][aoff[m][1]];
                a[m] = cvt8(lo, hi);
            }
        }
#pragma unroll
        for (int n = 0; n < 4; ++n)
            b[n] = *(const bf16x8*)&lds[buf][boff[n]];
#pragma unroll
        for (int m = 0; m < 4; ++m)
#pragma unroll
            for (int n = 0; n < 4; ++n)
                acc[m][n] = __builtin_amdgcn_mfma_f32_16x16x32_bf16(a[m], b[n], acc[m][n], 0, 0, 0);
    };

    stage(0, 0);
    __syncthreads();
#pragma unroll 1
    for (int kt = 0; kt < E; kt += 64) {
        stage(1, kt + 32);
        compute(0);
        __syncthreads();
        if (kt + 64 < E) stage(0, kt + 64);
        compute(1);
        __syncthreads();
    }

    const int ccol0 = bn0 + wn * 64 + r16;
    const int crow0 = am0 + wm * 64 + kg * 4;
    const float sc = ga.scale ? ga.scale[0] : 1.f;
    float bn_[4];
#pragma unroll
    for (int n = 0; n < 4; ++n) bn_[n] = ga.bias ? ga.bias[ccol0 + n * 16] : 0.f;
#pragma unroll
    for (int m = 0; m < 4; ++m)
#pragma unroll
        for (int n = 0; n < 4; ++n)
#pragma unroll
            for (int qq = 0; qq < 4; ++qq) {
                int row = crow0 + m * 16 + qq;
                int col = ccol0 + n * 16;
                short* p = (short*)(ga.C + (size_t)row * crstride) + col;
                *p = f2bfs(acc[m][n][qq] * sc + bn_[n]);
            }
}

// ============ fused: out = LN(q_emb + (kv_emb @ M^T + c)) * g + b ============
// 64 rows x 1024 cols, 8 waves, BK=32, 32 phases. Counted-vmcnt pipeline
// (T3+T4+T5): per phase, stage for p+2 is issued after the barrier that ends
// reads of the same buffer; the phase-end wait is vmcnt(9) (keep this phase's
// 9 loads in flight, drain the previous phase's 9) — never 0 in the loop.
// A is staged as f32 via global_load_lds (no reg round-trip -> no hidden
// compiler vmcnt(0)); cvt to bf16 at ds_read time.
// LDS 144KB: A dbuf 2x8KB @0, B dbuf 2x64KB @16384. 1 block/CU (structural:
// acc=128 AGPR + ~128 VGPR -> 2 waves/SIMD).
struct FArgs {
    const float* kv;   // [32768][1024] f32  (GEMM A)
    const short* M;    // [1024][1024] bf16  [n][k], alpha folded
    const float* c;    // [1024] f32, alpha folded
    const float* q;    // [32768][1024] f32  (residual emb)
    const float* g;
    const float* b;
    float* out;        // [32768][1024] f32
};

__global__ __launch_bounds__(512, 2) void fused_gemm_ln(FArgs f0, FArgs f1) {
    // pair-scheduling swizzle: consecutive slots on one XCD alternate tables at
    // the SAME mb, so the pair shares emb panels (kv of one = residual of other).
    const int bid = blockIdx.x;
    const int u = bid >> 3, xcd = bid & 7;
    const int z = u & 1;
    const int mb = xcd * 64 + (u >> 1);
    const FArgs fa = z ? f1 : f0;
    const int r0 = mb * 64;

    __shared__ __align__(16) char lds[147456];

    const int t = threadIdx.x;
    const int l = t & 63, w = t >> 6;
    const int r16 = l & 15, kg = l >> 4;

    // ---- staging source maps (inverse-swizzled) ----
    // B: 64KB/step; chunk c: gi=c*512+t; row=gi>>2, slot=gi&3 (16B units)
    int bsrc[8];
#pragma unroll
    for (int c = 0; c < 8; ++c) {
        int gi = c * 512 + t;
        int row = gi >> 2, slot = gi & 3;
        bsrc[c] = row * 2048 + (slot ^ ((row >> 1) & 3)) * 16;
    }
    // A: 8KB/step; gi=t; row=gi>>3, slot=gi&7 (16B units, 128B f32 rows)
    const char* Abase = (const char*)fa.kv + (size_t)(r0 + (t >> 3)) * 4096
                        + ((t & 7) ^ ((t >> 3) & 7)) * 16;

    auto stageB = [&](int buf, int kt) {
#pragma unroll
        for (int c = 0; c < 8; ++c)
            gload16((const char*)fa.M + bsrc[c] + kt * 2,
                    &lds[16384 + buf * 65536 + c * 8192 + w * 1024]);
    };
    auto stageA = [&](int buf, int kt) {
        gload16(Abase + (size_t)kt * 4, &lds[buf * 8192 + w * 1024]);
    };

    // ---- read-side swizzled offsets ----
    int aoff0[4], aoff1[4], boff[8];
#pragma unroll
    for (int m = 0; m < 4; ++m) {
        int row = m * 16 + r16;
        aoff0[m] = row * 128 + ((kg * 2) ^ (row & 7)) * 16;
        aoff1[m] = row * 128 + ((kg * 2 + 1) ^ (row & 7)) * 16;
    }
#pragma unroll
    for (int n = 0; n < 8; ++n) {
        int row = w * 128 + n * 16 + r16;
        boff[n] = 16384 + row * 64 + (kg ^ ((row >> 1) & 3)) * 16;
    }

    f32x4 acc[4][8] = {};

    auto phase = [&](int buf, int p) {
        const int abase = buf * 8192;
        const int bbase = buf * 65536;
        bf16x8 a[4], b[8];
#pragma unroll
        for (int m = 0; m < 4; ++m) {
            f32x4 lo = *(const f32x4*)&lds[abase + aoff0[m]];
            f32x4 hi = *(const f32x4*)&lds[abase + aoff1[m]];
            a[m] = cvt8(lo, hi);
        }
#pragma unroll
        for (int n = 0; n < 8; ++n)
            b[n] = *(const bf16x8*)&lds[bbase + boff[n]];
        asm volatile("s_waitcnt lgkmcnt(0)" ::: "memory");
        __builtin_amdgcn_sched_barrier(0);
        __builtin_amdgcn_s_barrier();            // all waves done reading buf
        const bool more = (p + 2) < 32;
        if (more) {                               // restage same buf for p+2
            stageA(buf, (p + 2) * 32);
            stageB(buf, (p + 2) * 32);
        }
        __builtin_amdgcn_s_setprio(1);
#pragma unroll
        for (int m = 0; m < 4; ++m)
#pragma unroll
            for (int n = 0; n < 8; ++n)
                acc[m][n] = __builtin_amdgcn_mfma_f32_16x16x32_bf16(a[m], b[n], acc[m][n], 0, 0, 0);
        __builtin_amdgcn_s_setprio(0);
        if (more) asm volatile("s_waitcnt vmcnt(9)" ::: "memory");  // prev phase's 9 done
        else      asm volatile("s_waitcnt vmcnt(0)" ::: "memory");  // tail drain
        __builtin_amdgcn_sched_barrier(0);
        __builtin_amdgcn_s_barrier();            // other buf staged for p+1
    };

    // prologue: stage buf0 (k=0) and buf1 (k=32); wait for buf0's 9
    stageA(0, 0);  stageB(0, 0);
    stageA(1, 32); stageB(1, 32);
    asm volatile("s_waitcnt vmcnt(9)" ::: "memory");
    __builtin_amdgcn_sched_barrier(0);
    __builtin_amdgcn_s_barrier();

#pragma unroll 1
    for (int p = 0; p < 32; p += 2) {
        phase(0, p);
        phase(1, p + 1);
    }
    __builtin_amdgcn_s_barrier();   // LDS free for LN scratch

    // ---- epilogue: residual + LayerNorm ----
    float* S  = (float*)lds;            // [64][8] row sums
    float* Q  = (float*)(lds + 2048);   // [64][8] row sumsq
    float* CB = (float*)(lds + 4096);   // [64][2] mean,rstd

    const int colbase = w * 128 + r16;
    float cf[8];
#pragma unroll
    for (int n = 0; n < 8; ++n) cf[n] = fa.c[colbase + n * 16];

    float sum_[4][4] = {}, sq_[4][4] = {};
#pragma unroll
    for (int m = 0; m < 4; ++m) {
#pragma unroll
        for (int n = 0; n < 8; ++n) {
#pragma unroll
            for (int qq = 0; qq < 4; ++qq) {
                int lrow = m * 16 + kg * 4 + qq;
                float x = acc[m][n][qq] + cf[n] + fa.q[(size_t)(r0 + lrow) * E + colbase + n * 16];
                acc[m][n][qq] = x;
                sum_[m][qq] += x;
                sq_[m][qq] += x * x;
            }
        }
    }
#pragma unroll
    for (int m = 0; m < 4; ++m)
#pragma unroll
        for (int qq = 0; qq < 4; ++qq)
#pragma unroll
            for (int o = 1; o < 16; o <<= 1) {
                sum_[m][qq] += __shfl_xor(sum_[m][qq], o);
                sq_[m][qq] += __shfl_xor(sq_[m][qq], o);
            }
#pragma unroll
    for (int m = 0; m < 4; ++m)
#pragma unroll
        for (int qq = 0; qq < 4; ++qq)
            if (r16 == m * 4 + qq) {
                int lrow = m * 16 + kg * 4 + qq;
                S[lrow * 8 + w] = sum_[m][qq];
                Q[lrow * 8 + w] = sq_[m][qq];
            }
    __syncthreads();
    if (t < 64) {
        f32x4 s0 = *(const f32x4*)(S + t * 8);
        f32x4 s1 = *(const f32x4*)(S + t * 8 + 4);
        f32x4 q0 = *(const f32x4*)(Q + t * 8);
        f32x4 q1 = *(const f32x4*)(Q + t * 8 + 4);
        float ss = s0[0] + s0[1] + s0[2] + s0[3] + s1[0] + s1[1] + s1[2] + s1[3];
        float qs = q0[0] + q0[1] + q0[2] + q0[3] + q1[0] + q1[1] + q1[2] + q1[3];
        float mean = ss * (1.0f / E);
        float var = qs * (1.0f / E) - mean * mean;
        CB[t * 2] = mean;
        CB[t * 2 + 1] = rsqrtf(var + 1e-5f);
    }
    __syncthreads();

    float gf[8], bf_[8];
#pragma unroll
    for (int n = 0; n < 8; ++n) {
        gf[n] = fa.g[colbase + n * 16];
        bf_[n] = fa.b[colbase + n * 16];
    }
#pragma unroll
    for (int m = 0; m < 4; ++m)
#pragma unroll
        for (int qq = 0; qq < 4; ++qq) {
            int lrow = m * 16 + kg * 4 + qq;
            float mean = CB[lrow * 2], rstd = CB[lrow * 2 + 1];
            float* op = fa.out + (size_t)(r0 + lrow) * E + colbase;
#pragma unroll
            for (int n = 0; n < 8; ++n)
                op[n * 16] = (acc[m][n][qq] - mean) * rstd * gf[n] + bf_[n];
        }
}

extern "C" void kernel_launch(void* const* d_in, const int* in_sizes, int n_in,
                              void* d_out, int out_size, void* d_ws, size_t ws_size,
                              hipStream_t stream) {
    const float* user_emb = (const float*)d_in[0];
    const float* item_emb = (const float*)d_in[1];
    const float* u2i_in_w = (const float*)d_in[2];
    const float* u2i_in_b = (const float*)d_in[3];
    const float* u2i_out_w = (const float*)d_in[4];
    const float* u2i_out_b = (const float*)d_in[5];
    const float* i2u_in_w = (const float*)d_in[6];
    const float* i2u_in_b = (const float*)d_in[7];
    const float* i2u_out_w = (const float*)d_in[8];
    const float* i2u_out_b = (const float*)d_in[9];
    const float* user_g = (const float*)d_in[10];
    const float* user_b = (const float*)d_in[11];
    const float* item_g = (const float*)d_in[12];
    const float* item_b = (const float*)d_in[13];
    const float* alpha = (const float*)d_in[14];
    const float* beta = (const float*)d_in[15];

    float* out_u = (float*)d_out;
    float* out_i = out_u + (size_t)NB * E;

    // workspace (~8.4 MB)
    short* WvT1 = (short*)d_ws;
    short* WvT2 = WvT1 + (size_t)E * E;
    short* M1 = WvT2 + (size_t)E * E;
    short* M2 = M1 + (size_t)E * E;
    float* c1 = (float*)(M2 + (size_t)E * E);
    float* c2 = c1 + E;

    const dim3 b256(256);

    // 1) WvT = transpose(in_w[2E:3E]) in bf16
    wv_transpose<<<dim3(32, 32, 2), dim3(32, 8), 0, stream>>>(
        u2i_in_w + 2 * (size_t)E * E, WvT1, i2u_in_w + 2 * (size_t)E * E, WvT2);

    // 2) c = scale * (O @ bv + ob)
    bias_fuse<<<dim3(E, 1, 2), b256, 0, stream>>>(
        u2i_out_w, u2i_in_b + 2 * E, u2i_out_b, alpha, c1,
        i2u_out_w, i2u_in_b + 2 * E, i2u_out_b, beta, c2);

    // 3) M = scale * (O @ Wv)   bf16 [n][k]
    gemm_bt<false><<<dim3(8 * 8 * 2), b256, 0, stream>>>(
        GemmArgs{(const char*)u2i_out_w, WvT1, nullptr, alpha, (char*)M1},
        GemmArgs{(const char*)i2u_out_w, WvT2, nullptr, beta, (char*)M2},
        8, 4096, 2048);

    // 4) fused GEMM + residual + LayerNorm (1024 blocks x 512 threads)
    fused_gemm_ln<<<dim3(1024), dim3(512), 0, stream>>>(
        FArgs{item_emb, M1, c1, user_emb, user_g, user_b, out_u},
        FArgs{user_emb, M2, c2, item_emb, item_g, item_b, out_i});
}

// Round 8
// 349.922 us; speedup vs baseline: 5.6645x; 1.0180x over previous
//
#include <hip/hip_runtime.h>
#include <cstdint>
#include <cstddef>

#define E 1024
#define NB 32768
#define BM 128
#define BN 128

typedef __attribute__((ext_vector_type(4))) float f32x4;
typedef __attribute__((ext_vector_type(8))) short bf16x8;
typedef __attribute__((ext_vector_type(4))) short s16x4;

__device__ __forceinline__ short f2bfs(float x) {
    __bf16 h = (__bf16)x;
    return __builtin_bit_cast(short, h);
}
__device__ __forceinline__ float bf2f(short u) {
    union { unsigned u; float f; } v;
    v.u = ((unsigned)(unsigned short)u) << 16;
    return v.f;
}
__device__ __forceinline__ bf16x8 cvt8(f32x4 lo, f32x4 hi) {
    bf16x8 r;
#pragma unroll
    for (int j = 0; j < 4; ++j) { r[j] = f2bfs(lo[j]); r[j + 4] = f2bfs(hi[j]); }
    return r;
}

__device__ __forceinline__ void gload16(const void* g, void* l) {
    __builtin_amdgcn_global_load_lds(
        (__attribute__((address_space(1))) void*)g,
        (__attribute__((address_space(3))) void*)l, 16, 0, 0);
}

// ---------------- transpose f32 -> bf16 (Wv -> WvT) ----------------
__global__ __launch_bounds__(256) void wv_transpose(const float* W0, short* T0,
                                                    const float* W1, short* T1) {
    const float* W = blockIdx.z ? W1 : W0;
    short* T = blockIdx.z ? T1 : T0;
    __shared__ float tile[32][33];
    const int j0 = blockIdx.x * 32, i0 = blockIdx.y * 32;
    const int tx = threadIdx.x, ty = threadIdx.y; // (32,8)
#pragma unroll
    for (int r = 0; r < 4; ++r)
        tile[ty + 8 * r][tx] = W[(size_t)(i0 + ty + 8 * r) * E + j0 + tx];
    __syncthreads();
#pragma unroll
    for (int r = 0; r < 4; ++r)
        T[(size_t)(j0 + ty + 8 * r) * E + i0 + tx] = f2bfs(tile[tx][ty + 8 * r]);
}

// ---------------- c[n] = scale * (sum_i O[n][i]*bv[i] + ob[n]) ----------------
__global__ __launch_bounds__(256) void bias_fuse(const float* O0, const float* bv0, const float* ob0, const float* s0, float* c0,
                                                 const float* O1, const float* bv1, const float* ob1, const float* s1, float* c1) {
    const float* O  = blockIdx.z ? O1 : O0;
    const float* bv = blockIdx.z ? bv1 : bv0;
    const float* ob = blockIdx.z ? ob1 : ob0;
    const float* sc = blockIdx.z ? s1 : s0;
    float* c = blockIdx.z ? c1 : c0;
    const int n = blockIdx.x, t = threadIdx.x;
    float s = 0.f;
    for (int i = t; i < E; i += 256) s += O[(size_t)n * E + i] * bv[i];
#pragma unroll
    for (int o = 32; o; o >>= 1) s += __shfl_down(s, o);
    __shared__ float rs[4];
    if ((t & 63) == 0) rs[t >> 6] = s;
    __syncthreads();
    if (t == 0) c[n] = sc[0] * (rs[0] + rs[1] + rs[2] + rs[3] + ob[n]);
}

// ---------------- small GEMM (round-3 proven): C = scale * A @ B^T ----------------
struct GemmArgs {
    const char* A;
    const short* B;
    const float* bias;
    const float* scale;
    char* C;
};

template <bool ABF16>
__global__ __launch_bounds__(256, ABF16 ? 4 : 3) void gemm_bt(GemmArgs g0, GemmArgs g1,
                                                              int mb, int arstride, int crstride) {
    const int nwg = gridDim.x;
    const int q = nwg >> 3;
    const int wgid = (blockIdx.x & 7) * q + (blockIdx.x >> 3);
    const int per = mb * 8;
    const int z = wgid / per;
    const int rem = wgid - z * per;
    const int bx = rem >> 3;
    const int by = rem & 7;
    GemmArgs ga = z ? g1 : g0;

    constexpr int ABYTES = ABF16 ? 8192 : 16384;
    constexpr int BUFB = ABYTES + 8192;
    __shared__ __align__(16) char lds[2][BUFB];

    const int t = threadIdx.x;
    const int l = t & 63, w = t >> 6;
    const int am0 = bx * BM, bn0 = by * BN;

    const char* gA[ABF16 ? 2 : 4];
    if constexpr (ABF16) {
#pragma unroll
        for (int i = 0; i < 2; ++i) {
            int c = i * 4 + w;
            int row = c * 16 + (l >> 2);
            int slot = (l & 3) ^ ((row >> 1) & 3);
            gA[i] = ga.A + (size_t)(am0 + row) * arstride + slot * 16;
        }
    } else {
#pragma unroll
        for (int i = 0; i < 4; ++i) {
            int c = i * 4 + w;
            int row = c * 8 + (l >> 3);
            int slot = (l & 7) ^ (row & 7);
            gA[i] = ga.A + (size_t)(am0 + row) * arstride + slot * 16;
        }
    }
    const short* gB[2];
#pragma unroll
    for (int i = 0; i < 2; ++i) {
        int c = i * 4 + w;
        int row = c * 16 + (l >> 2);
        int slot = (l & 3) ^ ((row >> 1) & 3);
        gB[i] = ga.B + (size_t)(bn0 + row) * E + slot * 8;
    }

    auto stage = [&](int buf, int kt) {
        if constexpr (ABF16) {
#pragma unroll
            for (int i = 0; i < 2; ++i)
                gload16(gA[i] + (size_t)kt * 2, &lds[buf][(i * 4 + w) * 1024]);
        } else {
#pragma unroll
            for (int i = 0; i < 4; ++i)
                gload16(gA[i] + (size_t)kt * 4, &lds[buf][(i * 4 + w) * 1024]);
        }
#pragma unroll
        for (int i = 0; i < 2; ++i)
            gload16(gB[i] + kt, &lds[buf][ABYTES + (i * 4 + w) * 1024]);
    };

    const int wm = w >> 1, wn = w & 1;
    const int r16 = l & 15, kg = l >> 4;
    int aoff[4][ABF16 ? 1 : 2], boff[4];
#pragma unroll
    for (int m = 0; m < 4; ++m) {
        int row = wm * 64 + m * 16 + r16;
        if constexpr (ABF16) {
            aoff[m][0] = row * 64 + (kg ^ ((row >> 1) & 3)) * 16;
        } else {
            aoff[m][0] = row * 128 + ((kg * 2) ^ (row & 7)) * 16;
            aoff[m][1] = row * 128 + ((kg * 2 + 1) ^ (row & 7)) * 16;
        }
    }
#pragma unroll
    for (int n = 0; n < 4; ++n) {
        int row = wn * 64 + n * 16 + r16;
        boff[n] = ABYTES + row * 64 + (kg ^ ((row >> 1) & 3)) * 16;
    }

    f32x4 acc[4][4] = {};

    auto compute = [&](int buf) {
        bf16x8 a[4], b[4];
#pragma unroll
        for (int m = 0; m < 4; ++m) {
            if constexpr (ABF16) {
                a[m] = *(const bf16x8*)&lds[buf][aoff[m][0]];
            } else {
                f32x4 lo = *(const f32x4*)&lds[buf][aoff[m][0]];
                f32x4 hi = *(const f32x4*)&lds[buf][aoff[m][1]];
                a[m] = cvt8(lo, hi);
            }
        }
#pragma unroll
        for (int n = 0; n < 4; ++n)
            b[n] = *(const bf16x8*)&lds[buf][boff[n]];
#pragma unroll
        for (int m = 0; m < 4; ++m)
#pragma unroll
            for (int n = 0; n < 4; ++n)
                acc[m][n] = __builtin_amdgcn_mfma_f32_16x16x32_bf16(a[m], b[n], acc[m][n], 0, 0, 0);
    };

    stage(0, 0);
    __syncthreads();
#pragma unroll 1
    for (int kt = 0; kt < E; kt += 64) {
        stage(1, kt + 32);
        compute(0);
        __syncthreads();
        if (kt + 64 < E) stage(0, kt + 64);
        compute(1);
        __syncthreads();
    }

    const int ccol0 = bn0 + wn * 64 + r16;
    const int crow0 = am0 + wm * 64 + kg * 4;
    const float sc = ga.scale ? ga.scale[0] : 1.f;
    float bn_[4];
#pragma unroll
    for (int n = 0; n < 4; ++n) bn_[n] = ga.bias ? ga.bias[ccol0 + n * 16] : 0.f;
#pragma unroll
    for (int m = 0; m < 4; ++m)
#pragma unroll
        for (int n = 0; n < 4; ++n)
#pragma unroll
            for (int qq = 0; qq < 4; ++qq) {
                int row = crow0 + m * 16 + qq;
                int col = ccol0 + n * 16;
                short* p = (short*)(ga.C + (size_t)row * crstride) + col;
                *p = f2bfs(acc[m][n][qq] * sc + bn_[n]);
            }
}

// ============ fused: out = LN(q_emb + (kv_emb @ M^T + c)) * g + b ============
// 64 rows x 1024 cols, 8 waves, BK=32, 32 phases, counted-vmcnt pipeline.
// A: bf16, reg-staged (T14): global f32x4 load 2 phases early -> cvt -> 8B
// ds_write into 64B-row XOR-swizzled layout (round-4/6 proven, ~0 conflicts).
// B: bf16 via global_load_lds DMA. Per phase 9 vm-events (8 B-DMA + 1 A-load)
// -> steady-state s_waitcnt vmcnt(9); tail: 8 (p=28,29), 0 (p>=30).
// LDS 139KB: A dbuf 2x4KB @0, B dbuf 2x64KB @8192. 1 block/CU (structural).
struct FArgs {
    const float* kv;   // [32768][1024] f32  (GEMM A)
    const short* M;    // [1024][1024] bf16  [n][k], alpha folded
    const float* c;    // [1024] f32, alpha folded
    const float* q;    // [32768][1024] f32  (residual emb)
    const float* g;
    const float* b;
    float* out;        // [32768][1024] f32
};

__global__ __launch_bounds__(512, 2) void fused_gemm_ln(FArgs f0, FArgs f1) {
    // pair-scheduling swizzle: consecutive slots on one XCD alternate tables at
    // the SAME mb, so the pair shares emb panels (kv of one = residual of other).
    const int bid = blockIdx.x;
    const int u = bid >> 3, xcd = bid & 7;
    const int z = u & 1;
    const int mb = xcd * 64 + (u >> 1);
    const FArgs fa = z ? f1 : f0;
    const int r0 = mb * 64;

    __shared__ __align__(16) char lds[139264];

    const int t = threadIdx.x;
    const int l = t & 63, w = t >> 6;
    const int r16 = l & 15, kg = l >> 4;

    // ---- B staging map (inverse-swizzled source, linear LDS dest) ----
    int bsrc[8];
#pragma unroll
    for (int c = 0; c < 8; ++c) {
        int gi = c * 512 + t;
        int row = gi >> 2, slot = gi & 3;
        bsrc[c] = row * 2048 + (slot ^ ((row >> 1) & 3)) * 16;
    }
    // ---- A commit map (reg-staged): thread t -> row t>>3, 8B sub-slot t&7 ----
    const int ar = t >> 3, ach = t & 7;
    const float* asrc = fa.kv + (size_t)(r0 + ar) * E + ach * 4;
    const int awoff = ar * 64 + (((ach >> 1) ^ ((ar >> 1) & 3)) * 16) + (ach & 1) * 8;

    // ---- read-side swizzled offsets (A: bf16 64B rows; B @8192) ----
    int aoff[4], boff[8];
#pragma unroll
    for (int m = 0; m < 4; ++m) {
        int row = m * 16 + r16;
        aoff[m] = row * 64 + (kg ^ ((row >> 1) & 3)) * 16;
    }
#pragma unroll
    for (int n = 0; n < 8; ++n) {
        int row = w * 128 + n * 16 + r16;
        boff[n] = 8192 + row * 64 + (kg ^ ((row >> 1) & 3)) * 16;
    }

    f32x4 acc[4][8] = {};

    auto stageB = [&](int buf, int kt) {
#pragma unroll
        for (int c = 0; c < 8; ++c)
            gload16((const char*)fa.M + bsrc[c] + kt * 2,
                    &lds[8192 + buf * 65536 + c * 8192 + w * 1024]);
    };
    auto commitA = [&](int buf, f32x4 av) {
        s16x4 v;
#pragma unroll
        for (int j = 0; j < 4; ++j) v[j] = f2bfs(av[j]);
        *(s16x4*)&lds[buf * 4096 + awoff] = v;
    };

    // phase p reads buf = p&1; after mid-barrier, restages the SAME buf for p+2
    // (B via DMA, A via commit of the reg loaded at phase p-2) and issues the
    // A-load for phase p+2's commit (k = (p+4)*32).
    auto phase = [&](int buf, int p, f32x4& areg) {
        bf16x8 a[4], b[8];
#pragma unroll
        for (int m = 0; m < 4; ++m)
            a[m] = *(const bf16x8*)&lds[buf * 4096 + aoff[m]];
#pragma unroll
        for (int n = 0; n < 8; ++n)
            b[n] = *(const bf16x8*)&lds[buf * 65536 + boff[n]];
        asm volatile("s_waitcnt lgkmcnt(0)" ::: "memory");
        __builtin_amdgcn_sched_barrier(0);
        __builtin_amdgcn_s_barrier();             // all waves done reading buf
        __builtin_amdgcn_sched_barrier(0);
        if (p + 2 < 32) {
            stageB(buf, (p + 2) * 32);            // 8 DMA
            commitA(buf, areg);                   // cvt + ds_write (reg from p-2)
        }
        if (p + 4 < 32)
            areg = *(const f32x4*)(asrc + (p + 4) * 32);  // 1 vm event
        __builtin_amdgcn_s_setprio(1);
#pragma unroll
        for (int m = 0; m < 4; ++m)
#pragma unroll
            for (int n = 0; n < 8; ++n)
                acc[m][n] = __builtin_amdgcn_mfma_f32_16x16x32_bf16(a[m], b[n], acc[m][n], 0, 0, 0);
        __builtin_amdgcn_s_setprio(0);
        if (p <= 27)      asm volatile("s_waitcnt vmcnt(9)" ::: "memory");
        else if (p <= 29) asm volatile("s_waitcnt vmcnt(8)" ::: "memory");
        else              asm volatile("s_waitcnt vmcnt(0)" ::: "memory");
        asm volatile("s_waitcnt lgkmcnt(0)" ::: "memory");  // commitA visible
        __builtin_amdgcn_sched_barrier(0);
        __builtin_amdgcn_s_barrier();             // next buf ready
    };

    // ---- prologue: both buffers staged; A regs 2 phases ahead ----
    f32x4 aE = *(const f32x4*)(asrc);           // k=0   -> commit buf0
    f32x4 aO = *(const f32x4*)(asrc + 32);      // k=32  -> commit buf1
    stageB(0, 0);
    stageB(1, 32);
    commitA(0, aE);                              // compiler-managed vm wait
    commitA(1, aO);
    aE = *(const f32x4*)(asrc + 64);             // phase 0's commit (k=64)
    aO = *(const f32x4*)(asrc + 96);             // phase 1's commit (k=96)
    asm volatile("s_waitcnt vmcnt(10)" ::: "memory");   // buf0's 8 B done
    asm volatile("s_waitcnt lgkmcnt(0)" ::: "memory");  // commits visible
    __builtin_amdgcn_sched_barrier(0);
    __builtin_amdgcn_s_barrier();

#pragma unroll 1
    for (int p = 0; p < 32; p += 2) {
        phase(0, p, aE);
        phase(1, p + 1, aO);
    }

    // ---- epilogue: residual + LayerNorm ----
    float* S  = (float*)lds;            // [64][8] row sums
    float* Q  = (float*)(lds + 2048);   // [64][8] row sumsq
    float* CB = (float*)(lds + 4096);   // [64][2] mean,rstd

    const int colbase = w * 128 + r16;
    float cf[8];
#pragma unroll
    for (int n = 0; n < 8; ++n) cf[n] = fa.c[colbase + n * 16];

    float sum_[4][4] = {}, sq_[4][4] = {};
#pragma unroll
    for (int m = 0; m < 4; ++m) {
#pragma unroll
        for (int n = 0; n < 8; ++n) {
#pragma unroll
            for (int qq = 0; qq < 4; ++qq) {
                int lrow = m * 16 + kg * 4 + qq;
                float x = acc[m][n][qq] + cf[n] + fa.q[(size_t)(r0 + lrow) * E + colbase + n * 16];
                acc[m][n][qq] = x;
                sum_[m][qq] += x;
                sq_[m][qq] += x * x;
            }
        }
    }
#pragma unroll
    for (int m = 0; m < 4; ++m)
#pragma unroll
        for (int qq = 0; qq < 4; ++qq)
#pragma unroll
            for (int o = 1; o < 16; o <<= 1) {
                sum_[m][qq] += __shfl_xor(sum_[m][qq], o);
                sq_[m][qq] += __shfl_xor(sq_[m][qq], o);
            }
#pragma unroll
    for (int m = 0; m < 4; ++m)
#pragma unroll
        for (int qq = 0; qq < 4; ++qq)
            if (r16 == m * 4 + qq) {
                int lrow = m * 16 + kg * 4 + qq;
                S[lrow * 8 + w] = sum_[m][qq];
                Q[lrow * 8 + w] = sq_[m][qq];
            }
    __syncthreads();
    if (t < 64) {
        f32x4 s0 = *(const f32x4*)(S + t * 8);
        f32x4 s1 = *(const f32x4*)(S + t * 8 + 4);
        f32x4 q0 = *(const f32x4*)(Q + t * 8);
        f32x4 q1 = *(const f32x4*)(Q + t * 8 + 4);
        float ss = s0[0] + s0[1] + s0[2] + s0[3] + s1[0] + s1[1] + s1[2] + s1[3];
        float qs = q0[0] + q0[1] + q0[2] + q0[3] + q1[0] + q1[1] + q1[2] + q1[3];
        float mean = ss * (1.0f / E);
        float var = qs * (1.0f / E) - mean * mean;
        CB[t * 2] = mean;
        CB[t * 2 + 1] = rsqrtf(var + 1e-5f);
    }
    __syncthreads();

    float gf[8], bf_[8];
#pragma unroll
    for (int n = 0; n < 8; ++n) {
        gf[n] = fa.g[colbase + n * 16];
        bf_[n] = fa.b[colbase + n * 16];
    }
#pragma unroll
    for (int m = 0; m < 4; ++m)
#pragma unroll
        for (int qq = 0; qq < 4; ++qq) {
            int lrow = m * 16 + kg * 4 + qq;
            float mean = CB[lrow * 2], rstd = CB[lrow * 2 + 1];
            float* op = fa.out + (size_t)(r0 + lrow) * E + colbase;
#pragma unroll
            for (int n = 0; n < 8; ++n)
                op[n * 16] = (acc[m][n][qq] - mean) * rstd * gf[n] + bf_[n];
        }
}

extern "C" void kernel_launch(void* const* d_in, const int* in_sizes, int n_in,
                              void* d_out, int out_size, void* d_ws, size_t ws_size,
                              hipStream_t stream) {
    const float* user_emb = (const float*)d_in[0];
    const float* item_emb = (const float*)d_in[1];
    const float* u2i_in_w = (const float*)d_in[2];
    const float* u2i_in_b = (const float*)d_in[3];
    const float* u2i_out_w = (const float*)d_in[4];
    const float* u2i_out_b = (const float*)d_in[5];
    const float* i2u_in_w = (const float*)d_in[6];
    const float* i2u_in_b = (const float*)d_in[7];
    const float* i2u_out_w = (const float*)d_in[8];
    const float* i2u_out_b = (const float*)d_in[9];
    const float* user_g = (const float*)d_in[10];
    const float* user_b = (const float*)d_in[11];
    const float* item_g = (const float*)d_in[12];
    const float* item_b = (const float*)d_in[13];
    const float* alpha = (const float*)d_in[14];
    const float* beta = (const float*)d_in[15];

    float* out_u = (float*)d_out;
    float* out_i = out_u + (size_t)NB * E;

    // workspace (~8.4 MB)
    short* WvT1 = (short*)d_ws;
    short* WvT2 = WvT1 + (size_t)E * E;
    short* M1 = WvT2 + (size_t)E * E;
    short* M2 = M1 + (size_t)E * E;
    float* c1 = (float*)(M2 + (size_t)E * E);
    float* c2 = c1 + E;

    const dim3 b256(256);

    // 1) WvT = transpose(in_w[2E:3E]) in bf16
    wv_transpose<<<dim3(32, 32, 2), dim3(32, 8), 0, stream>>>(
        u2i_in_w + 2 * (size_t)E * E, WvT1, i2u_in_w + 2 * (size_t)E * E, WvT2);

    // 2) c = scale * (O @ bv + ob)
    bias_fuse<<<dim3(E, 1, 2), b256, 0, stream>>>(
        u2i_out_w, u2i_in_b + 2 * E, u2i_out_b, alpha, c1,
        i2u_out_w, i2u_in_b + 2 * E, i2u_out_b, beta, c2);

    // 3) M = scale * (O @ Wv)   bf16 [n][k]
    gemm_bt<false><<<dim3(8 * 8 * 2), b256, 0, stream>>>(
        GemmArgs{(const char*)u2i_out_w, WvT1, nullptr, alpha, (char*)M1},
        GemmArgs{(const char*)i2u_out_w, WvT2, nullptr, beta, (char*)M2},
        8, 4096, 2048);

    // 4) fused GEMM + residual + LayerNorm (1024 blocks x 512 threads)
    fused_gemm_ln<<<dim3(1024), dim3(512), 0, stream>>>(
        FArgs{item_emb, M1, c1, user_emb, user_g, user_b, out_u},
        FArgs{user_emb, M2, c2, item_emb, item_g, item_b, out_i});
}